// Round 1
// baseline (3520.258 us; speedup 1.0000x reference)
//
#include <hip/hip_runtime.h>
#include <math.h>

#define S 128
#define R 384
#define CM 256
#define CZ 128
#define H 8
#define D 32
#define INFB 1e9f
#define LN_EPS 1e-5f

__device__ inline float wave_reduce_sum(float v) {
    #pragma unroll
    for (int o = 32; o > 0; o >>= 1) v += __shfl_xor(v, o, 64);
    return v;
}

__device__ inline float wave_reduce_max(float v) {
    #pragma unroll
    for (int o = 32; o > 0; o >>= 1) v = fmaxf(v, __shfl_xor(v, o, 64));
    return v;
}

// ---------------------------------------------------------------------------
// z_bias[h][i][j] = sum_c LN(z[i,j,:])[c] * w_z[c][h]
// one wave per (i,j); lane l handles channels l and l+64
__global__ __launch_bounds__(64) void zbias_kernel(
    const float* __restrict__ z, const float* __restrict__ lnw,
    const float* __restrict__ lnb, const float* __restrict__ wz,
    float* __restrict__ zbias) {
    int j = blockIdx.x, i = blockIdx.y;
    int l = threadIdx.x;
    const float* zp = z + ((size_t)i * R + j) * CZ;
    float x0 = zp[l], x1 = zp[l + 64];
    float mu = wave_reduce_sum(x0 + x1) * (1.0f / CZ);
    float d0 = x0 - mu, d1 = x1 - mu;
    float var = wave_reduce_sum(d0 * d0 + d1 * d1) * (1.0f / CZ);
    float rstd = rsqrtf(var + LN_EPS);
    float n0 = d0 * rstd * lnw[l] + lnb[l];
    float n1 = d1 * rstd * lnw[l + 64] + lnb[l + 64];
    #pragma unroll
    for (int h = 0; h < H; ++h) {
        float p = n0 * wz[l * H + h] + n1 * wz[(l + 64) * H + h];
        p = wave_reduce_sum(p);
        if (l == 0) zbias[((size_t)h * R + i) * R + j] = p;
    }
}

// ---------------------------------------------------------------------------
// Fused LN(m) + q/k/v/g projections. 8 rows per block, 256 threads.
// q scaled by 1/sqrt(D); g = sigmoid(. + b_g).
__global__ __launch_bounds__(256) void qkvg_kernel(
    const float* __restrict__ m, const float* __restrict__ lnw,
    const float* __restrict__ lnb,
    const float* __restrict__ wq, const float* __restrict__ wk,
    const float* __restrict__ wv, const float* __restrict__ wg,
    const float* __restrict__ bg,
    float* __restrict__ q, float* __restrict__ k,
    float* __restrict__ v, float* __restrict__ g) {
    __shared__ float a[8][CM];
    int t = threadIdx.x;
    int wave = t >> 6, lane = t & 63;
    size_t row0 = (size_t)blockIdx.x * 8;
    // LN stats: wave w handles rows 2w and 2w+1 (lane covers 4 channels)
    for (int rr = wave * 2; rr < wave * 2 + 2; ++rr) {
        const float4* mp = (const float4*)(m + (row0 + rr) * CM);
        float4 x = mp[lane];
        float ss = x.x + x.y + x.z + x.w;
        float sq = x.x * x.x + x.y * x.y + x.z * x.z + x.w * x.w;
        ss = wave_reduce_sum(ss);
        sq = wave_reduce_sum(sq);
        float mu = ss * (1.0f / CM);
        float var = sq * (1.0f / CM) - mu * mu;
        float rstd = rsqrtf(var + LN_EPS);
        int c = lane * 4;
        a[rr][c]     = (x.x - mu) * rstd * lnw[c]     + lnb[c];
        a[rr][c + 1] = (x.y - mu) * rstd * lnw[c + 1] + lnb[c + 1];
        a[rr][c + 2] = (x.z - mu) * rstd * lnw[c + 2] + lnb[c + 2];
        a[rr][c + 3] = (x.w - mu) * rstd * lnw[c + 3] + lnb[c + 3];
    }
    __syncthreads();
    float accq[8] = {}, acck[8] = {}, accv[8] = {}, accg[8] = {};
    for (int kk = 0; kk < CM; ++kk) {
        float wqv = wq[kk * 256 + t];
        float wkv = wk[kk * 256 + t];
        float wvv = wv[kk * 256 + t];
        float wgv = wg[kk * 256 + t];
        #pragma unroll
        for (int rr = 0; rr < 8; ++rr) {
            float av = a[rr][kk];
            accq[rr] = fmaf(av, wqv, accq[rr]);
            acck[rr] = fmaf(av, wkv, acck[rr]);
            accv[rr] = fmaf(av, wvv, accv[rr]);
            accg[rr] = fmaf(av, wgv, accg[rr]);
        }
    }
    float bgv = bg[t];
    #pragma unroll
    for (int rr = 0; rr < 8; ++rr) {
        size_t off = (row0 + rr) * 256 + t;
        q[off] = accq[rr] * 0.17677669529663687f;  // 1/sqrt(32)
        k[off] = acck[rr];
        v[off] = accv[rr];
        g[off] = 1.0f / (1.0f + __expf(-(accg[rr] + bgv)));
    }
}

// ---------------------------------------------------------------------------
// Attention: one block (384 threads) per (s, h, q-row).
// Phase 1: logits over 384 keys (thread t = key row). Phase 2: softmax.
// Phase 3: PV with 12 chunks x 32 d.
__global__ __launch_bounds__(384) void attn_kernel(
    const float* __restrict__ q, const float* __restrict__ k,
    const float* __restrict__ v, const float* __restrict__ g,
    const float* __restrict__ mask, const float* __restrict__ zb,
    float* __restrict__ o) {
    int qr = blockIdx.x, h = blockIdx.y, s = blockIdx.z;
    int t = threadIdx.x;
    int wave = t >> 6, lane = t & 63;
    __shared__ float qsh[32];
    __shared__ float lsh[384];
    __shared__ float red1[6];
    __shared__ float red2[6];
    __shared__ float pred[12][32];
    size_t qoff = (((size_t)s * R + qr) * H + h) * D;
    if (t < 32) qsh[t] = q[qoff + t];
    __syncthreads();
    // logits
    int kr = t;
    const float4* kp = (const float4*)(k + (((size_t)s * R + kr) * H + h) * D);
    const float4* qp4 = (const float4*)qsh;
    float acc = 0.f;
    #pragma unroll
    for (int i2 = 0; i2 < 8; ++i2) {
        float4 kv = kp[i2];
        float4 qv = qp4[i2];
        acc += qv.x * kv.x + qv.y * kv.y + qv.z * kv.z + qv.w * kv.w;
    }
    float logit = acc + INFB * (mask[(size_t)s * R + kr] - 1.0f)
                      + zb[((size_t)h * R + qr) * R + kr];
    // block max
    float wm = wave_reduce_max(logit);
    if (lane == 0) red1[wave] = wm;
    __syncthreads();
    float bmax = fmaxf(fmaxf(fmaxf(red1[0], red1[1]), fmaxf(red1[2], red1[3])),
                       fmaxf(red1[4], red1[5]));
    float e = __expf(logit - bmax);
    lsh[t] = e;
    float wsum = wave_reduce_sum(e);
    if (lane == 0) red2[wave] = wsum;
    __syncthreads();  // lsh visible + red2 ready
    float denom = red2[0] + red2[1] + red2[2] + red2[3] + red2[4] + red2[5];
    float inv = 1.0f / denom;
    // PV: thread t -> d = t&31, chunk = t>>5 (12 chunks of 32 keys)
    int d = t & 31;
    int chunk = t >> 5;
    int kr0 = chunk * 32;
    float po = 0.f;
    for (int j2 = 0; j2 < 32; ++j2) {
        int kkr = kr0 + j2;
        po += lsh[kkr] * v[(((size_t)s * R + kkr) * H + h) * D + d];
    }
    pred[chunk][d] = po;
    __syncthreads();
    if (t < 32) {
        float sum = 0.f;
        #pragma unroll
        for (int c = 0; c < 12; ++c) sum += pred[c][t];
        sum *= inv;
        o[qoff + t] = sum * g[qoff + t];
    }
}

// ---------------------------------------------------------------------------
// out[s,r,c] = sum_k o_row[k] * w_o[k][c] + b_o[c]; 8 rows/block
__global__ __launch_bounds__(256) void outproj_kernel(
    const float* __restrict__ o, const float* __restrict__ wo,
    const float* __restrict__ bo, float* __restrict__ out) {
    __shared__ float a[8][256];
    int t = threadIdx.x;
    size_t row0 = (size_t)blockIdx.x * 8;
    for (int rr = 0; rr < 8; ++rr)
        a[rr][t] = o[(row0 + rr) * 256 + t];
    __syncthreads();
    float acc[8] = {};
    for (int kk = 0; kk < 256; ++kk) {
        float w = wo[kk * 256 + t];
        #pragma unroll
        for (int rr = 0; rr < 8; ++rr)
            acc[rr] = fmaf(a[rr][kk], w, acc[rr]);
    }
    float b = bo[t];
    #pragma unroll
    for (int rr = 0; rr < 8; ++rr)
        out[(row0 + rr) * 256 + t] = acc[rr] + b;
}

extern "C" void kernel_launch(void* const* d_in, const int* in_sizes, int n_in,
                              void* d_out, int out_size, void* d_ws, size_t ws_size,
                              hipStream_t stream) {
    (void)in_sizes; (void)n_in; (void)out_size; (void)ws_size;
    const float* m      = (const float*)d_in[0];
    const float* z      = (const float*)d_in[1];
    const float* mask   = (const float*)d_in[2];
    const float* ln_m_w = (const float*)d_in[3];
    const float* ln_m_b = (const float*)d_in[4];
    const float* ln_z_w = (const float*)d_in[5];
    const float* ln_z_b = (const float*)d_in[6];
    const float* w_z    = (const float*)d_in[7];
    const float* w_q    = (const float*)d_in[8];
    const float* w_k    = (const float*)d_in[9];
    const float* w_v    = (const float*)d_in[10];
    const float* w_g    = (const float*)d_in[11];
    const float* b_g    = (const float*)d_in[12];
    const float* w_o    = (const float*)d_in[13];
    const float* b_o    = (const float*)d_in[14];
    float* out = (float*)d_out;
    float* ws  = (float*)d_ws;

    const size_t NR = (size_t)S * R;  // 49152 rows
    float* q  = ws;
    float* k  = q + NR * 256;
    float* v  = k + NR * 256;
    float* g  = v + NR * 256;
    float* o  = g + NR * 256;
    float* zb = o + NR * 256;  // H*R*R floats

    zbias_kernel<<<dim3(R, R), 64, 0, stream>>>(z, ln_z_w, ln_z_b, w_z, zb);
    qkvg_kernel<<<NR / 8, 256, 0, stream>>>(m, ln_m_w, ln_m_b,
                                            w_q, w_k, w_v, w_g, b_g,
                                            q, k, v, g);
    attn_kernel<<<dim3(R, H, S), 384, 0, stream>>>(q, k, v, g, mask, zb, o);
    outproj_kernel<<<NR / 8, 256, 0, stream>>>(o, w_o, b_o, out);
}

// Round 2
// 2330.282 us; speedup vs baseline: 1.5107x; 1.5107x over previous
//
#include <hip/hip_runtime.h>
#include <math.h>

#define S 128
#define R 384
#define CM 256
#define CZ 128
#define H 8
#define D 32
#define INFB 1e9f
#define LN_EPS 1e-5f

__device__ inline float wave_reduce_sum(float v) {
    #pragma unroll
    for (int o = 32; o > 0; o >>= 1) v += __shfl_xor(v, o, 64);
    return v;
}

__device__ inline float wave_reduce_max(float v) {
    #pragma unroll
    for (int o = 32; o > 0; o >>= 1) v = fmaxf(v, __shfl_xor(v, o, 64));
    return v;
}

// ---------------------------------------------------------------------------
// z_bias[h][i][j] = sum_c LN(z[i,j,:])[c] * w_z[c][h]
// one wave per (i,j); lane l handles channels l and l+64
__global__ __launch_bounds__(64) void zbias_kernel(
    const float* __restrict__ z, const float* __restrict__ lnw,
    const float* __restrict__ lnb, const float* __restrict__ wz,
    float* __restrict__ zbias) {
    int j = blockIdx.x, i = blockIdx.y;
    int l = threadIdx.x;
    const float* zp = z + ((size_t)i * R + j) * CZ;
    float x0 = zp[l], x1 = zp[l + 64];
    float mu = wave_reduce_sum(x0 + x1) * (1.0f / CZ);
    float d0 = x0 - mu, d1 = x1 - mu;
    float var = wave_reduce_sum(d0 * d0 + d1 * d1) * (1.0f / CZ);
    float rstd = rsqrtf(var + LN_EPS);
    float n0 = d0 * rstd * lnw[l] + lnb[l];
    float n1 = d1 * rstd * lnw[l + 64] + lnb[l + 64];
    #pragma unroll
    for (int h = 0; h < H; ++h) {
        float p = n0 * wz[l * H + h] + n1 * wz[(l + 64) * H + h];
        p = wave_reduce_sum(p);
        if (l == 0) zbias[((size_t)h * R + i) * R + j] = p;
    }
}

// ---------------------------------------------------------------------------
// Fused LN(m) + q/k/v/g projections. 8 rows per block, 256 threads.
__global__ __launch_bounds__(256) void qkvg_kernel(
    const float* __restrict__ m, const float* __restrict__ lnw,
    const float* __restrict__ lnb,
    const float* __restrict__ wq, const float* __restrict__ wk,
    const float* __restrict__ wv, const float* __restrict__ wg,
    const float* __restrict__ bg,
    float* __restrict__ q, float* __restrict__ k,
    float* __restrict__ v, float* __restrict__ g) {
    __shared__ float a[8][CM];
    int t = threadIdx.x;
    int wave = t >> 6, lane = t & 63;
    size_t row0 = (size_t)blockIdx.x * 8;
    for (int rr = wave * 2; rr < wave * 2 + 2; ++rr) {
        const float4* mp = (const float4*)(m + (row0 + rr) * CM);
        float4 x = mp[lane];
        float ss = x.x + x.y + x.z + x.w;
        float sq = x.x * x.x + x.y * x.y + x.z * x.z + x.w * x.w;
        ss = wave_reduce_sum(ss);
        sq = wave_reduce_sum(sq);
        float mu = ss * (1.0f / CM);
        float var = sq * (1.0f / CM) - mu * mu;
        float rstd = rsqrtf(var + LN_EPS);
        int c = lane * 4;
        a[rr][c]     = (x.x - mu) * rstd * lnw[c]     + lnb[c];
        a[rr][c + 1] = (x.y - mu) * rstd * lnw[c + 1] + lnb[c + 1];
        a[rr][c + 2] = (x.z - mu) * rstd * lnw[c + 2] + lnb[c + 2];
        a[rr][c + 3] = (x.w - mu) * rstd * lnw[c + 3] + lnb[c + 3];
    }
    __syncthreads();
    float accq[8] = {}, acck[8] = {}, accv[8] = {}, accg[8] = {};
    for (int kk = 0; kk < CM; ++kk) {
        float wqv = wq[kk * 256 + t];
        float wkv = wk[kk * 256 + t];
        float wvv = wv[kk * 256 + t];
        float wgv = wg[kk * 256 + t];
        #pragma unroll
        for (int rr = 0; rr < 8; ++rr) {
            float av = a[rr][kk];
            accq[rr] = fmaf(av, wqv, accq[rr]);
            acck[rr] = fmaf(av, wkv, acck[rr]);
            accv[rr] = fmaf(av, wvv, accv[rr]);
            accg[rr] = fmaf(av, wgv, accg[rr]);
        }
    }
    float bgv = bg[t];
    #pragma unroll
    for (int rr = 0; rr < 8; ++rr) {
        size_t off = (row0 + rr) * 256 + t;
        q[off] = accq[rr] * 0.17677669529663687f;  // 1/sqrt(32)
        k[off] = acck[rr];
        v[off] = accv[rr];
        g[off] = 1.0f / (1.0f + __expf(-(accg[rr] + bgv)));
    }
}

// ---------------------------------------------------------------------------
// Attention v2: one block (384 threads) per (s, h).
// K in registers (thread t = key row t), V staged once in LDS.
// q-rows processed 4 at a time with batched softmax reductions.
__global__ __launch_bounds__(384) void attn_kernel(
    const float* __restrict__ q, const float* __restrict__ k,
    const float* __restrict__ v, const float* __restrict__ g,
    const float* __restrict__ mask, const float* __restrict__ zb,
    float* __restrict__ o) {
    int h = blockIdx.x, s = blockIdx.y;
    int t = threadIdx.x;
    int wave = t >> 6, lane = t & 63;

    __shared__ float Vsh[384][33];     // padded: kills stride-32 conflicts
    __shared__ float psh[384][4];      // P transposed: float4 read per key
    __shared__ float pred[12][4][32];  // PV partials per key-chunk
    __shared__ float qsh[4][32];
    __shared__ float redm[4][6];
    __shared__ float reds[4][6];

    size_t base = (size_t)s * R * (H * D) + (size_t)h * D;  // row 0, this head

    // stage K into registers, V into LDS (each read exactly once per block)
    float kreg[32];
    {
        const float4* kp = (const float4*)(k + base + (size_t)t * (H * D));
        const float4* vp = (const float4*)(v + base + (size_t)t * (H * D));
        #pragma unroll
        for (int i = 0; i < 8; ++i) {
            float4 kv = kp[i];
            kreg[4 * i + 0] = kv.x; kreg[4 * i + 1] = kv.y;
            kreg[4 * i + 2] = kv.z; kreg[4 * i + 3] = kv.w;
            float4 vv = vp[i];
            Vsh[t][4 * i + 0] = vv.x; Vsh[t][4 * i + 1] = vv.y;
            Vsh[t][4 * i + 2] = vv.z; Vsh[t][4 * i + 3] = vv.w;
        }
    }
    float mval = INFB * (mask[(size_t)s * R + t] - 1.0f);
    const float* zrow = zb + (size_t)h * R * R + t;  // + q*R per row
    __syncthreads();

    for (int q0 = 0; q0 < R; q0 += 4) {
        // stage 4 q rows
        if (t < 128) {
            int r = t >> 5, d = t & 31;
            qsh[r][d] = q[base + (size_t)(q0 + r) * (H * D) + d];
        }
        float zr[4];
        #pragma unroll
        for (int r = 0; r < 4; ++r) zr[r] = zrow[(size_t)(q0 + r) * R];
        __syncthreads();

        // logits: thread t = key t, 4 q rows
        float logit[4];
        #pragma unroll
        for (int r = 0; r < 4; ++r) {
            const float4* q4 = (const float4*)qsh[r];
            float acc = 0.f;
            #pragma unroll
            for (int i = 0; i < 8; ++i) {
                float4 qv = q4[i];
                acc = fmaf(qv.x, kreg[4 * i + 0], acc);
                acc = fmaf(qv.y, kreg[4 * i + 1], acc);
                acc = fmaf(qv.z, kreg[4 * i + 2], acc);
                acc = fmaf(qv.w, kreg[4 * i + 3], acc);
            }
            logit[r] = acc + mval + zr[r];
            float wm = wave_reduce_max(logit[r]);
            if (lane == 0) redm[r][wave] = wm;
        }
        __syncthreads();

        // softmax numerators + sums
        float ev[4];
        #pragma unroll
        for (int r = 0; r < 4; ++r) {
            float bm = fmaxf(fmaxf(fmaxf(redm[r][0], redm[r][1]),
                                   fmaxf(redm[r][2], redm[r][3])),
                             fmaxf(redm[r][4], redm[r][5]));
            ev[r] = __expf(logit[r] - bm);
            float ws = wave_reduce_sum(ev[r]);
            if (lane == 0) reds[r][wave] = ws;
        }
        *(float4*)psh[t] = make_float4(ev[0], ev[1], ev[2], ev[3]);
        __syncthreads();

        float inv[4];
        #pragma unroll
        for (int r = 0; r < 4; ++r) {
            float dn = reds[r][0] + reds[r][1] + reds[r][2] +
                       reds[r][3] + reds[r][4] + reds[r][5];
            inv[r] = 1.0f / dn;
        }

        // PV: chunk c = t>>5 (12 chunks of 32 keys), d = t&31
        int c = t >> 5, d = t & 31;
        float po[4] = {0.f, 0.f, 0.f, 0.f};
        int kk0 = c * 32;
        #pragma unroll
        for (int j = 0; j < 32; ++j) {
            int kk = kk0 + j;
            float vv = Vsh[kk][d];
            float4 p4 = *(const float4*)psh[kk];
            po[0] = fmaf(p4.x, vv, po[0]);
            po[1] = fmaf(p4.y, vv, po[1]);
            po[2] = fmaf(p4.z, vv, po[2]);
            po[3] = fmaf(p4.w, vv, po[3]);
        }
        #pragma unroll
        for (int r = 0; r < 4; ++r) pred[c][r][d] = po[r];
        __syncthreads();

        // reduce 12 chunks, gate, write
        if (t < 128) {
            int r = t >> 5, dd = t & 31;
            float sum = 0.f;
            #pragma unroll
            for (int c2 = 0; c2 < 12; ++c2) sum += pred[c2][r][dd];
            size_t off = base + (size_t)(q0 + r) * (H * D) + dd;
            o[off] = sum * inv[r] * g[off];
        }
        // next-iter writes (qsh at step A) are ordered by the sync at the
        // top of the next iteration's stage-B; pred readers re-sync there too.
        __syncthreads();
    }
}

// ---------------------------------------------------------------------------
// out[s,r,c] = sum_k o_row[k] * w_o[k][c] + b_o[c]; 8 rows/block
__global__ __launch_bounds__(256) void outproj_kernel(
    const float* __restrict__ o, const float* __restrict__ wo,
    const float* __restrict__ bo, float* __restrict__ out) {
    __shared__ float a[8][256];
    int t = threadIdx.x;
    size_t row0 = (size_t)blockIdx.x * 8;
    for (int rr = 0; rr < 8; ++rr)
        a[rr][t] = o[(row0 + rr) * 256 + t];
    __syncthreads();
    float acc[8] = {};
    for (int kk = 0; kk < 256; ++kk) {
        float w = wo[kk * 256 + t];
        #pragma unroll
        for (int rr = 0; rr < 8; ++rr)
            acc[rr] = fmaf(a[rr][kk], w, acc[rr]);
    }
    float b = bo[t];
    #pragma unroll
    for (int rr = 0; rr < 8; ++rr)
        out[(row0 + rr) * 256 + t] = acc[rr] + b;
}

extern "C" void kernel_launch(void* const* d_in, const int* in_sizes, int n_in,
                              void* d_out, int out_size, void* d_ws, size_t ws_size,
                              hipStream_t stream) {
    (void)in_sizes; (void)n_in; (void)out_size; (void)ws_size;
    const float* m      = (const float*)d_in[0];
    const float* z      = (const float*)d_in[1];
    const float* mask   = (const float*)d_in[2];
    const float* ln_m_w = (const float*)d_in[3];
    const float* ln_m_b = (const float*)d_in[4];
    const float* ln_z_w = (const float*)d_in[5];
    const float* ln_z_b = (const float*)d_in[6];
    const float* w_z    = (const float*)d_in[7];
    const float* w_q    = (const float*)d_in[8];
    const float* w_k    = (const float*)d_in[9];
    const float* w_v    = (const float*)d_in[10];
    const float* w_g    = (const float*)d_in[11];
    const float* b_g    = (const float*)d_in[12];
    const float* w_o    = (const float*)d_in[13];
    const float* b_o    = (const float*)d_in[14];
    float* out = (float*)d_out;
    float* ws  = (float*)d_ws;

    const size_t NR = (size_t)S * R;  // 49152 rows
    float* q  = ws;
    float* k  = q + NR * 256;
    float* v  = k + NR * 256;
    float* g  = v + NR * 256;
    float* o  = g + NR * 256;
    float* zb = o + NR * 256;  // H*R*R floats

    zbias_kernel<<<dim3(R, R), 64, 0, stream>>>(z, ln_z_w, ln_z_b, w_z, zb);
    qkvg_kernel<<<NR / 8, 256, 0, stream>>>(m, ln_m_w, ln_m_b,
                                            w_q, w_k, w_v, w_g, b_g,
                                            q, k, v, g);
    attn_kernel<<<dim3(H, S), 384, 0, stream>>>(q, k, v, g, mask, zb, o);
    outproj_kernel<<<NR / 8, 256, 0, stream>>>(o, w_o, b_o, out);
}

// Round 3
// 978.015 us; speedup vs baseline: 3.5994x; 2.3827x over previous
//
#include <hip/hip_runtime.h>
#include <math.h>

#define S 128
#define R 384
#define CM 256
#define CZ 128
#define H 8
#define D 32
#define INFB 1e9f
#define LN_EPS 1e-5f

typedef short bf16x8 __attribute__((ext_vector_type(8)));
typedef float f32x4 __attribute__((ext_vector_type(4)));

__device__ inline float wave_reduce_sum(float v) {
    #pragma unroll
    for (int o = 32; o > 0; o >>= 1) v += __shfl_xor(v, o, 64);
    return v;
}

__device__ inline unsigned short f2bf(float f) {
    union { float f; unsigned int u; } x; x.f = f;
    unsigned int r = x.u + 0x7fffu + ((x.u >> 16) & 1u);
    return (unsigned short)(r >> 16);
}

// ---------------------------------------------------------------------------
// z_bias[h][i][j] = sum_c LN(z[i,j,:])[c] * w_z[c][h]
__global__ __launch_bounds__(64) void zbias_kernel(
    const float* __restrict__ z, const float* __restrict__ lnw,
    const float* __restrict__ lnb, const float* __restrict__ wz,
    float* __restrict__ zbias) {
    int j = blockIdx.x, i = blockIdx.y;
    int l = threadIdx.x;
    const float* zp = z + ((size_t)i * R + j) * CZ;
    float x0 = zp[l], x1 = zp[l + 64];
    float mu = wave_reduce_sum(x0 + x1) * (1.0f / CZ);
    float d0 = x0 - mu, d1 = x1 - mu;
    float var = wave_reduce_sum(d0 * d0 + d1 * d1) * (1.0f / CZ);
    float rstd = rsqrtf(var + LN_EPS);
    float n0 = d0 * rstd * lnw[l] + lnb[l];
    float n1 = d1 * rstd * lnw[l + 64] + lnb[l + 64];
    #pragma unroll
    for (int h = 0; h < H; ++h) {
        float p = n0 * wz[l * H + h] + n1 * wz[(l + 64) * H + h];
        p = wave_reduce_sum(p);
        if (l == 0) zbias[((size_t)h * R + i) * R + j] = p;
    }
}

// ---------------------------------------------------------------------------
// Fused LN(m) + q/k/v/g projections. 8 rows per block, 256 threads.
__global__ __launch_bounds__(256) void qkvg_kernel(
    const float* __restrict__ m, const float* __restrict__ lnw,
    const float* __restrict__ lnb,
    const float* __restrict__ wq, const float* __restrict__ wk,
    const float* __restrict__ wv, const float* __restrict__ wg,
    const float* __restrict__ bg,
    float* __restrict__ q, float* __restrict__ k,
    float* __restrict__ v, float* __restrict__ g) {
    __shared__ float a[8][CM];
    int t = threadIdx.x;
    int wave = t >> 6, lane = t & 63;
    size_t row0 = (size_t)blockIdx.x * 8;
    for (int rr = wave * 2; rr < wave * 2 + 2; ++rr) {
        const float4* mp = (const float4*)(m + (row0 + rr) * CM);
        float4 x = mp[lane];
        float ss = x.x + x.y + x.z + x.w;
        float sq = x.x * x.x + x.y * x.y + x.z * x.z + x.w * x.w;
        ss = wave_reduce_sum(ss);
        sq = wave_reduce_sum(sq);
        float mu = ss * (1.0f / CM);
        float var = sq * (1.0f / CM) - mu * mu;
        float rstd = rsqrtf(var + LN_EPS);
        int c = lane * 4;
        a[rr][c]     = (x.x - mu) * rstd * lnw[c]     + lnb[c];
        a[rr][c + 1] = (x.y - mu) * rstd * lnw[c + 1] + lnb[c + 1];
        a[rr][c + 2] = (x.z - mu) * rstd * lnw[c + 2] + lnb[c + 2];
        a[rr][c + 3] = (x.w - mu) * rstd * lnw[c + 3] + lnb[c + 3];
    }
    __syncthreads();
    float accq[8] = {}, acck[8] = {}, accv[8] = {}, accg[8] = {};
    for (int kk = 0; kk < CM; ++kk) {
        float wqv = wq[kk * 256 + t];
        float wkv = wk[kk * 256 + t];
        float wvv = wv[kk * 256 + t];
        float wgv = wg[kk * 256 + t];
        #pragma unroll
        for (int rr = 0; rr < 8; ++rr) {
            float av = a[rr][kk];
            accq[rr] = fmaf(av, wqv, accq[rr]);
            acck[rr] = fmaf(av, wkv, acck[rr]);
            accv[rr] = fmaf(av, wvv, accv[rr]);
            accg[rr] = fmaf(av, wgv, accg[rr]);
        }
    }
    float bgv = bg[t];
    #pragma unroll
    for (int rr = 0; rr < 8; ++rr) {
        size_t off = (row0 + rr) * 256 + t;
        q[off] = accq[rr] * 0.17677669529663687f;  // 1/sqrt(32)
        k[off] = acck[rr];
        v[off] = accv[rr];
        g[off] = 1.0f / (1.0f + __expf(-(accg[rr] + bgv)));
    }
}

// ---------------------------------------------------------------------------
// Attention v3: MFMA bf16, one block (512 thr, 8 waves) per (s, h).
// Wave owns 48 q-rows. Q in regs (bf16 A-frags). K read from global (L2:
// grid.x=h => all blocks of head h on XCD h => K + zb slices L2-local).
// V^T staged once in LDS (bf16). P per-wave in LDS (XOR-swizzled).
// No barriers in the K-loop. Softmax without max-subtract (logits O(1);
// masked keys -> exp(-1e9)=0).
__global__ __launch_bounds__(512) void attn_kernel(
    const float* __restrict__ q, const float* __restrict__ k,
    const float* __restrict__ v, const float* __restrict__ g,
    const float* __restrict__ mask, const float* __restrict__ zb,
    float* __restrict__ o) {
    int h = blockIdx.x, s = blockIdx.y;
    int t = threadIdx.x;
    int lane = t & 63, wave = t >> 6;
    int l15 = lane & 15, l4 = lane >> 4;

    __shared__ __attribute__((aligned(16))) unsigned short VTsh[32 * 408];
    __shared__ __attribute__((aligned(16))) unsigned short Psh[8 * 48 * 32];

    size_t base = ((size_t)s * R) * 256 + (size_t)h * 32;  // row-0 elem offset

    // ---- stage V^T (bf16) into LDS: VTsh[d][key], stride 408
    for (int it = 0; it < 6; ++it) {
        int idx = t + it * 512;
        int key = idx >> 3;
        int c4 = (idx & 7) << 2;
        const float4 vv = *(const float4*)(v + base + (size_t)key * 256 + c4);
        VTsh[(c4 + 0) * 408 + key] = f2bf(vv.x);
        VTsh[(c4 + 1) * 408 + key] = f2bf(vv.y);
        VTsh[(c4 + 2) * 408 + key] = f2bf(vv.z);
        VTsh[(c4 + 3) * 408 + key] = f2bf(vv.w);
    }

    // ---- Q A-frags in registers (3 row-tiles x K=32)
    int wq0 = wave * 48;
    bf16x8 qf[3];
    #pragma unroll
    for (int rt = 0; rt < 3; ++rt) {
        const float* qp = q + base + (size_t)(wq0 + rt * 16 + l15) * 256 + l4 * 8;
        float4 a = *(const float4*)qp;
        float4 b = *(const float4*)(qp + 4);
        qf[rt][0] = (short)f2bf(a.x); qf[rt][1] = (short)f2bf(a.y);
        qf[rt][2] = (short)f2bf(a.z); qf[rt][3] = (short)f2bf(a.w);
        qf[rt][4] = (short)f2bf(b.x); qf[rt][5] = (short)f2bf(b.y);
        qf[rt][6] = (short)f2bf(b.z); qf[rt][7] = (short)f2bf(b.w);
    }
    __syncthreads();  // VTsh ready (only barrier in the kernel)

    f32x4 oacc[3][2];
    #pragma unroll
    for (int rt = 0; rt < 3; ++rt)
        #pragma unroll
        for (int dt = 0; dt < 2; ++dt)
            oacc[rt][dt] = (f32x4){0.f, 0.f, 0.f, 0.f};
    float pden[3][4] = {};

    const float* zbh = zb + (size_t)h * R * R;
    const int pbase = wave * 1536;  // 48*32 per-wave P slice

    for (int kt = 0; kt < R; kt += 32) {
        // K B-frags from global (bf16 on the fly)
        bf16x8 kf[2];
        float mv[2];
        #pragma unroll
        for (int ct = 0; ct < 2; ++ct) {
            int key = kt + ct * 16 + l15;
            const float* kp = k + base + (size_t)key * 256 + l4 * 8;
            float4 a = *(const float4*)kp;
            float4 b = *(const float4*)(kp + 4);
            kf[ct][0] = (short)f2bf(a.x); kf[ct][1] = (short)f2bf(a.y);
            kf[ct][2] = (short)f2bf(a.z); kf[ct][3] = (short)f2bf(a.w);
            kf[ct][4] = (short)f2bf(b.x); kf[ct][5] = (short)f2bf(b.y);
            kf[ct][6] = (short)f2bf(b.z); kf[ct][7] = (short)f2bf(b.w);
            mv[ct] = INFB * (mask[(size_t)s * R + key] - 1.0f);
        }

        // QK^T: S[48 x 32] via 6 MFMA (K=32 covers full D)
        const f32x4 z4 = {0.f, 0.f, 0.f, 0.f};
        f32x4 sfr[3][2];
        #pragma unroll
        for (int rt = 0; rt < 3; ++rt)
            #pragma unroll
            for (int ct = 0; ct < 2; ++ct)
                sfr[rt][ct] = __builtin_amdgcn_mfma_f32_16x16x32_bf16(
                    qf[rt], kf[ct], z4, 0, 0, 0);

        // bias + exp -> P (bf16, swizzled, wave-private)
        #pragma unroll
        for (int rt = 0; rt < 3; ++rt) {
            #pragma unroll
            for (int ct = 0; ct < 2; ++ct) {
                #pragma unroll
                for (int r = 0; r < 4; ++r) {
                    int row = rt * 16 + l4 * 4 + r;            // local q-row
                    int key = kt + ct * 16 + l15;
                    float zv = zbh[(size_t)(wq0 + row) * R + key];
                    float e = __expf(sfr[rt][ct][r] + mv[ct] + zv);
                    pden[rt][r] += e;
                    int ei = (row * 32 + ct * 16 + l15) ^ (((row >> 2) & 3) << 4);
                    Psh[pbase + ei] = f2bf(e);
                }
            }
        }

        // PV: O[48 x 32] += P[48 x 32] * V[32keys x 32d]
        #pragma unroll
        for (int rt = 0; rt < 3; ++rt) {
            int row = rt * 16 + l15;
            int ei = (row * 32 + l4 * 8) ^ (((row >> 2) & 3) << 4);
            bf16x8 pa = *(const bf16x8*)&Psh[pbase + ei];
            #pragma unroll
            for (int dt = 0; dt < 2; ++dt) {
                bf16x8 vbf = *(const bf16x8*)&VTsh[(dt * 16 + l15) * 408 + kt + l4 * 8];
                oacc[rt][dt] = __builtin_amdgcn_mfma_f32_16x16x32_bf16(
                    pa, vbf, oacc[rt][dt], 0, 0, 0);
            }
        }
    }

    // denominator: reduce across the 16 col-lanes (rows already per-lane)
    #pragma unroll
    for (int rt = 0; rt < 3; ++rt)
        #pragma unroll
        for (int r = 0; r < 4; ++r) {
            float d = pden[rt][r];
            d += __shfl_xor(d, 1, 64);
            d += __shfl_xor(d, 2, 64);
            d += __shfl_xor(d, 4, 64);
            d += __shfl_xor(d, 8, 64);
            pden[rt][r] = d;
        }

    // epilogue: normalize, gate, store
    #pragma unroll
    for (int rt = 0; rt < 3; ++rt) {
        #pragma unroll
        for (int r = 0; r < 4; ++r) {
            float inv = 1.0f / pden[rt][r];
            int qrow = wq0 + rt * 16 + l4 * 4 + r;
            #pragma unroll
            for (int dt = 0; dt < 2; ++dt) {
                size_t off = base + (size_t)qrow * 256 + dt * 16 + l15;
                o[off] = oacc[rt][dt][r] * inv * g[off];
            }
        }
    }
}

// ---------------------------------------------------------------------------
// out[s,r,c] = sum_k o_row[k] * w_o[k][c] + b_o[c]; 8 rows/block
__global__ __launch_bounds__(256) void outproj_kernel(
    const float* __restrict__ o, const float* __restrict__ wo,
    const float* __restrict__ bo, float* __restrict__ out) {
    __shared__ float a[8][256];
    int t = threadIdx.x;
    size_t row0 = (size_t)blockIdx.x * 8;
    for (int rr = 0; rr < 8; ++rr)
        a[rr][t] = o[(row0 + rr) * 256 + t];
    __syncthreads();
    float acc[8] = {};
    for (int kk = 0; kk < 256; ++kk) {
        float w = wo[kk * 256 + t];
        #pragma unroll
        for (int rr = 0; rr < 8; ++rr)
            acc[rr] = fmaf(a[rr][kk], w, acc[rr]);
    }
    float b = bo[t];
    #pragma unroll
    for (int rr = 0; rr < 8; ++rr)
        out[(row0 + rr) * 256 + t] = acc[rr] + b;
}

extern "C" void kernel_launch(void* const* d_in, const int* in_sizes, int n_in,
                              void* d_out, int out_size, void* d_ws, size_t ws_size,
                              hipStream_t stream) {
    (void)in_sizes; (void)n_in; (void)out_size; (void)ws_size;
    const float* m      = (const float*)d_in[0];
    const float* z      = (const float*)d_in[1];
    const float* mask   = (const float*)d_in[2];
    const float* ln_m_w = (const float*)d_in[3];
    const float* ln_m_b = (const float*)d_in[4];
    const float* ln_z_w = (const float*)d_in[5];
    const float* ln_z_b = (const float*)d_in[6];
    const float* w_z    = (const float*)d_in[7];
    const float* w_q    = (const float*)d_in[8];
    const float* w_k    = (const float*)d_in[9];
    const float* w_v    = (const float*)d_in[10];
    const float* w_g    = (const float*)d_in[11];
    const float* b_g    = (const float*)d_in[12];
    const float* w_o    = (const float*)d_in[13];
    const float* b_o    = (const float*)d_in[14];
    float* out = (float*)d_out;
    float* ws  = (float*)d_ws;

    const size_t NR = (size_t)S * R;  // 49152 rows
    float* q  = ws;
    float* k  = q + NR * 256;
    float* v  = k + NR * 256;
    float* g  = v + NR * 256;
    float* o  = g + NR * 256;
    float* zb = o + NR * 256;  // H*R*R floats

    zbias_kernel<<<dim3(R, R), 64, 0, stream>>>(z, ln_z_w, ln_z_b, w_z, zb);
    qkvg_kernel<<<NR / 8, 256, 0, stream>>>(m, ln_m_w, ln_m_b,
                                            w_q, w_k, w_v, w_g, b_g,
                                            q, k, v, g);
    attn_kernel<<<dim3(H, S), 512, 0, stream>>>(q, k, v, g, mask, zb, o);
    outproj_kernel<<<NR / 8, 256, 0, stream>>>(o, w_o, b_o, out);
}

// Round 4
// 595.768 us; speedup vs baseline: 5.9088x; 1.6416x over previous
//
#include <hip/hip_runtime.h>
#include <math.h>

#define S 128
#define R 384
#define CM 256
#define CZ 128
#define H 8
#define D 32
#define INFB 1e9f
#define LN_EPS 1e-5f

typedef unsigned short u16;
typedef short bf16x8 __attribute__((ext_vector_type(8)));
typedef float f32x4 __attribute__((ext_vector_type(4)));

__device__ inline float wave_reduce_sum(float v) {
    #pragma unroll
    for (int o = 32; o > 0; o >>= 1) v += __shfl_xor(v, o, 64);
    return v;
}

__device__ inline u16 f2bf(float f) {
    union { float f; unsigned int u; } x; x.f = f;
    unsigned int r = x.u + 0x7fffu + ((x.u >> 16) & 1u);
    return (u16)(r >> 16);
}

// ---------------------------------------------------------------------------
// Weight prep: Wt[mi][n][k] = src_mi[k][n] as bf16; mi: 0=q(scaled),1=k,2=v,3=g,4=o
__global__ __launch_bounds__(256) void wprep_kernel(
    const float* __restrict__ wq, const float* __restrict__ wk,
    const float* __restrict__ wv, const float* __restrict__ wg,
    const float* __restrict__ wo, u16* __restrict__ Wt) {
    int n = blockIdx.x & 255;
    int mi = blockIdx.x >> 8;
    int kc = threadIdx.x;
    const float* src = mi == 0 ? wq : mi == 1 ? wk : mi == 2 ? wv
                     : mi == 3 ? wg : wo;
    float val = src[(size_t)kc * 256 + n];
    if (mi == 0) val *= 0.17677669529663687f;  // 1/sqrt(32)
    Wt[((size_t)mi * 256 + n) * 256 + kc] = f2bf(val);
}

// ---------------------------------------------------------------------------
// LN(m) -> A bf16 [S*R][256]. 4 rows per block, wave per row.
__global__ __launch_bounds__(256) void lnm_kernel(
    const float* __restrict__ m, const float* __restrict__ lnw,
    const float* __restrict__ lnb, u16* __restrict__ A) {
    int t = threadIdx.x;
    int wave = t >> 6, lane = t & 63;
    size_t row = (size_t)blockIdx.x * 4 + wave;
    float4 x = ((const float4*)(m + row * 256))[lane];
    float ss = wave_reduce_sum(x.x + x.y + x.z + x.w);
    float sq = wave_reduce_sum(x.x * x.x + x.y * x.y + x.z * x.z + x.w * x.w);
    float mu = ss * (1.0f / 256.0f);
    float var = sq * (1.0f / 256.0f) - mu * mu;
    float rstd = rsqrtf(var + LN_EPS);
    int c = lane * 4;
    ushort4 o4;
    o4.x = f2bf((x.x - mu) * rstd * lnw[c]     + lnb[c]);
    o4.y = f2bf((x.y - mu) * rstd * lnw[c + 1] + lnb[c + 1]);
    o4.z = f2bf((x.z - mu) * rstd * lnw[c + 2] + lnb[c + 2]);
    o4.w = f2bf((x.w - mu) * rstd * lnw[c + 3] + lnb[c + 3]);
    ((ushort4*)(A + row * 256))[lane] = o4;
}

// ---------------------------------------------------------------------------
// z_bias[h][i][j]; 4 (i,j) pairs per block (wave per pair)
__global__ __launch_bounds__(256) void zbias_kernel(
    const float* __restrict__ z, const float* __restrict__ lnw,
    const float* __restrict__ lnb, const float* __restrict__ wz,
    float* __restrict__ zbias) {
    int wave = threadIdx.x >> 6, l = threadIdx.x & 63;
    int j = blockIdx.x * 4 + wave, i = blockIdx.y;
    const float* zp = z + ((size_t)i * R + j) * CZ;
    float x0 = zp[l], x1 = zp[l + 64];
    float mu = wave_reduce_sum(x0 + x1) * (1.0f / CZ);
    float d0 = x0 - mu, d1 = x1 - mu;
    float var = wave_reduce_sum(d0 * d0 + d1 * d1) * (1.0f / CZ);
    float rstd = rsqrtf(var + LN_EPS);
    float n0 = d0 * rstd * lnw[l] + lnb[l];
    float n1 = d1 * rstd * lnw[l + 64] + lnb[l + 64];
    #pragma unroll
    for (int h = 0; h < H; ++h) {
        float p = n0 * wz[l * H + h] + n1 * wz[(l + 64) * H + h];
        p = wave_reduce_sum(p);
        if (l == 0) zbias[((size_t)h * R + i) * R + j] = p;
    }
}

// ---------------------------------------------------------------------------
// qkvg GEMM: M=49152, K=256, one weight matrix per blockIdx.y.
// 512 thr / 8 waves, BM=128, wave tile 64x64, no LDS, no barriers.
__global__ __launch_bounds__(512) void qkvg_gemm(
    const u16* __restrict__ A, const u16* __restrict__ Wt,
    const float* __restrict__ bg,
    u16* __restrict__ q, u16* __restrict__ k, u16* __restrict__ v,
    float* __restrict__ g) {
    int nb = blockIdx.y;
    size_t row0 = (size_t)blockIdx.x * 128;
    int t = threadIdx.x, lane = t & 63, wave = t >> 6;
    int l15 = lane & 15, l4 = lane >> 4;
    int wm = (wave >> 2) * 64, wn = (wave & 3) * 64;
    const u16* B = Wt + (size_t)nb * 256 * 256;
    const u16* Ab = A + (row0 + wm + l15) * 256 + l4 * 8;
    const u16* Bb = B + (size_t)(wn + l15) * 256 + l4 * 8;

    f32x4 acc[4][4];
    #pragma unroll
    for (int mt = 0; mt < 4; ++mt)
        #pragma unroll
        for (int nt = 0; nt < 4; ++nt)
            acc[mt][nt] = (f32x4){0.f, 0.f, 0.f, 0.f};

    #pragma unroll
    for (int kk = 0; kk < 8; ++kk) {
        bf16x8 af[4], bfr[4];
        #pragma unroll
        for (int mt = 0; mt < 4; ++mt)
            af[mt] = *(const bf16x8*)(Ab + (size_t)mt * 16 * 256 + kk * 32);
        #pragma unroll
        for (int nt = 0; nt < 4; ++nt)
            bfr[nt] = *(const bf16x8*)(Bb + (size_t)nt * 16 * 256 + kk * 32);
        #pragma unroll
        for (int mt = 0; mt < 4; ++mt)
            #pragma unroll
            for (int nt = 0; nt < 4; ++nt)
                acc[mt][nt] = __builtin_amdgcn_mfma_f32_16x16x32_bf16(
                    af[mt], bfr[nt], acc[mt][nt], 0, 0, 0);
    }

    if (nb == 3) {
        #pragma unroll
        for (int nt = 0; nt < 4; ++nt) {
            int col = wn + nt * 16 + l15;
            float bgv = bg[col];
            #pragma unroll
            for (int mt = 0; mt < 4; ++mt)
                #pragma unroll
                for (int r = 0; r < 4; ++r) {
                    size_t row = row0 + wm + mt * 16 + l4 * 4 + r;
                    g[row * 256 + col] =
                        1.0f / (1.0f + __expf(-(acc[mt][nt][r] + bgv)));
                }
        }
    } else {
        u16* dst = nb == 0 ? q : nb == 1 ? k : v;
        #pragma unroll
        for (int nt = 0; nt < 4; ++nt) {
            int col = wn + nt * 16 + l15;
            #pragma unroll
            for (int mt = 0; mt < 4; ++mt)
                #pragma unroll
                for (int r = 0; r < 4; ++r) {
                    size_t row = row0 + wm + mt * 16 + l4 * 4 + r;
                    dst[row * 256 + col] = f2bf(acc[mt][nt][r]);
                }
        }
    }
}

// ---------------------------------------------------------------------------
// out GEMM: M=49152, N=256, K=256; A = o (bf16), +b_o, fp32 out.
__global__ __launch_bounds__(512) void out_gemm(
    const u16* __restrict__ A, const u16* __restrict__ Wt,
    const float* __restrict__ bo, float* __restrict__ out) {
    size_t row0 = (size_t)blockIdx.x * 128;
    int t = threadIdx.x, lane = t & 63, wave = t >> 6;
    int l15 = lane & 15, l4 = lane >> 4;
    int wm = (wave >> 2) * 64, wn = (wave & 3) * 64;
    const u16* Ab = A + (row0 + wm + l15) * 256 + l4 * 8;
    const u16* Bb = Wt + (size_t)(wn + l15) * 256 + l4 * 8;

    f32x4 acc[4][4];
    #pragma unroll
    for (int mt = 0; mt < 4; ++mt)
        #pragma unroll
        for (int nt = 0; nt < 4; ++nt)
            acc[mt][nt] = (f32x4){0.f, 0.f, 0.f, 0.f};

    #pragma unroll
    for (int kk = 0; kk < 8; ++kk) {
        bf16x8 af[4], bfr[4];
        #pragma unroll
        for (int mt = 0; mt < 4; ++mt)
            af[mt] = *(const bf16x8*)(Ab + (size_t)mt * 16 * 256 + kk * 32);
        #pragma unroll
        for (int nt = 0; nt < 4; ++nt)
            bfr[nt] = *(const bf16x8*)(Bb + (size_t)nt * 16 * 256 + kk * 32);
        #pragma unroll
        for (int mt = 0; mt < 4; ++mt)
            #pragma unroll
            for (int nt = 0; nt < 4; ++nt)
                acc[mt][nt] = __builtin_amdgcn_mfma_f32_16x16x32_bf16(
                    af[mt], bfr[nt], acc[mt][nt], 0, 0, 0);
    }

    #pragma unroll
    for (int nt = 0; nt < 4; ++nt) {
        int col = wn + nt * 16 + l15;
        float bov = bo[col];
        #pragma unroll
        for (int mt = 0; mt < 4; ++mt)
            #pragma unroll
            for (int r = 0; r < 4; ++r) {
                size_t row = row0 + wm + mt * 16 + l4 * 4 + r;
                out[row * 256 + col] = acc[mt][nt][r] + bov;
            }
    }
}

// ---------------------------------------------------------------------------
// Attention: MFMA bf16, one block (512 thr, 8 waves) per (s, h).
// q/k/v are bf16 (direct frag loads); o written bf16.
__global__ __launch_bounds__(512) void attn_kernel(
    const u16* __restrict__ q, const u16* __restrict__ k,
    const u16* __restrict__ v, const float* __restrict__ g,
    const float* __restrict__ mask, const float* __restrict__ zb,
    u16* __restrict__ o) {
    int h = blockIdx.x, s = blockIdx.y;
    int t = threadIdx.x;
    int lane = t & 63, wave = t >> 6;
    int l15 = lane & 15, l4 = lane >> 4;

    __shared__ __attribute__((aligned(16))) u16 VTsh[32 * 408];
    __shared__ __attribute__((aligned(16))) u16 Psh[8 * 48 * 32];

    size_t base = ((size_t)s * R) * 256 + (size_t)h * 32;  // bf16 elem offset

    // stage V^T into LDS: VTsh[d][key], stride 408
    for (int it = 0; it < 6; ++it) {
        int idx = t + it * 512;
        int key = idx >> 3;
        int c4 = (idx & 7) << 2;
        ushort4 vv = *(const ushort4*)(v + base + (size_t)key * 256 + c4);
        VTsh[(c4 + 0) * 408 + key] = vv.x;
        VTsh[(c4 + 1) * 408 + key] = vv.y;
        VTsh[(c4 + 2) * 408 + key] = vv.z;
        VTsh[(c4 + 3) * 408 + key] = vv.w;
    }

    int wq0 = wave * 48;
    bf16x8 qf[3];
    #pragma unroll
    for (int rt = 0; rt < 3; ++rt)
        qf[rt] = *(const bf16x8*)(q + base +
                                  (size_t)(wq0 + rt * 16 + l15) * 256 + l4 * 8);
    __syncthreads();  // VTsh ready

    f32x4 oacc[3][2];
    #pragma unroll
    for (int rt = 0; rt < 3; ++rt)
        #pragma unroll
        for (int dt = 0; dt < 2; ++dt)
            oacc[rt][dt] = (f32x4){0.f, 0.f, 0.f, 0.f};
    float pden[3][4] = {};

    const float* zbh = zb + (size_t)h * R * R;
    const int pbase = wave * 1536;

    for (int kt = 0; kt < R; kt += 32) {
        bf16x8 kf[2];
        float mv[2];
        #pragma unroll
        for (int ct = 0; ct < 2; ++ct) {
            int key = kt + ct * 16 + l15;
            kf[ct] = *(const bf16x8*)(k + base + (size_t)key * 256 + l4 * 8);
            mv[ct] = INFB * (mask[(size_t)s * R + key] - 1.0f);
        }

        const f32x4 z4 = {0.f, 0.f, 0.f, 0.f};
        f32x4 sfr[3][2];
        #pragma unroll
        for (int rt = 0; rt < 3; ++rt)
            #pragma unroll
            for (int ct = 0; ct < 2; ++ct)
                sfr[rt][ct] = __builtin_amdgcn_mfma_f32_16x16x32_bf16(
                    qf[rt], kf[ct], z4, 0, 0, 0);

        #pragma unroll
        for (int rt = 0; rt < 3; ++rt) {
            #pragma unroll
            for (int ct = 0; ct < 2; ++ct) {
                #pragma unroll
                for (int r = 0; r < 4; ++r) {
                    int row = rt * 16 + l4 * 4 + r;
                    int key = kt + ct * 16 + l15;
                    float zv = zbh[(size_t)(wq0 + row) * R + key];
                    float e = __expf(sfr[rt][ct][r] + mv[ct] + zv);
                    pden[rt][r] += e;
                    int ei = (row * 32 + ct * 16 + l15) ^ (((row >> 2) & 3) << 4);
                    Psh[pbase + ei] = f2bf(e);
                }
            }
        }

        #pragma unroll
        for (int rt = 0; rt < 3; ++rt) {
            int row = rt * 16 + l15;
            int ei = (row * 32 + l4 * 8) ^ (((row >> 2) & 3) << 4);
            bf16x8 pa = *(const bf16x8*)&Psh[pbase + ei];
            #pragma unroll
            for (int dt = 0; dt < 2; ++dt) {
                bf16x8 vbf = *(const bf16x8*)&VTsh[(dt * 16 + l15) * 408 + kt + l4 * 8];
                oacc[rt][dt] = __builtin_amdgcn_mfma_f32_16x16x32_bf16(
                    pa, vbf, oacc[rt][dt], 0, 0, 0);
            }
        }
    }

    #pragma unroll
    for (int rt = 0; rt < 3; ++rt)
        #pragma unroll
        for (int r = 0; r < 4; ++r) {
            float d = pden[rt][r];
            d += __shfl_xor(d, 1, 64);
            d += __shfl_xor(d, 2, 64);
            d += __shfl_xor(d, 4, 64);
            d += __shfl_xor(d, 8, 64);
            pden[rt][r] = d;
        }

    #pragma unroll
    for (int rt = 0; rt < 3; ++rt) {
        #pragma unroll
        for (int r = 0; r < 4; ++r) {
            float inv = 1.0f / pden[rt][r];
            int qrow = wq0 + rt * 16 + l4 * 4 + r;
            #pragma unroll
            for (int dt = 0; dt < 2; ++dt) {
                size_t off = base + (size_t)qrow * 256 + dt * 16 + l15;
                o[off] = f2bf(oacc[rt][dt][r] * inv * g[off]);
            }
        }
    }
}

extern "C" void kernel_launch(void* const* d_in, const int* in_sizes, int n_in,
                              void* d_out, int out_size, void* d_ws, size_t ws_size,
                              hipStream_t stream) {
    (void)in_sizes; (void)n_in; (void)out_size; (void)ws_size;
    const float* m      = (const float*)d_in[0];
    const float* z      = (const float*)d_in[1];
    const float* mask   = (const float*)d_in[2];
    const float* ln_m_w = (const float*)d_in[3];
    const float* ln_m_b = (const float*)d_in[4];
    const float* ln_z_w = (const float*)d_in[5];
    const float* ln_z_b = (const float*)d_in[6];
    const float* w_z    = (const float*)d_in[7];
    const float* w_q    = (const float*)d_in[8];
    const float* w_k    = (const float*)d_in[9];
    const float* w_v    = (const float*)d_in[10];
    const float* w_g    = (const float*)d_in[11];
    const float* b_g    = (const float*)d_in[12];
    const float* w_o    = (const float*)d_in[13];
    const float* b_o    = (const float*)d_in[14];
    float* out = (float*)d_out;
    char* wsb = (char*)d_ws;

    const size_t NR = (size_t)S * R;  // 49152 rows
    u16*   A   = (u16*)wsb;                      wsb += NR * 256 * 2;
    u16*   q   = (u16*)wsb;                      wsb += NR * 256 * 2;
    u16*   k   = (u16*)wsb;                      wsb += NR * 256 * 2;
    u16*   v   = (u16*)wsb;                      wsb += NR * 256 * 2;
    u16*   o   = (u16*)wsb;                      wsb += NR * 256 * 2;
    float* g   = (float*)wsb;                    wsb += NR * 256 * 4;
    float* zbp = (float*)wsb;                    wsb += (size_t)H * R * R * 4;
    u16*   Wt  = (u16*)wsb;                      wsb += (size_t)5 * 256 * 256 * 2;

    wprep_kernel<<<5 * 256, 256, 0, stream>>>(w_q, w_k, w_v, w_g, w_o, Wt);
    lnm_kernel<<<NR / 4, 256, 0, stream>>>(m, ln_m_w, ln_m_b, A);
    zbias_kernel<<<dim3(R / 4, R), 256, 0, stream>>>(z, ln_z_w, ln_z_b, w_z, zbp);
    qkvg_gemm<<<dim3(NR / 128, 4), 512, 0, stream>>>(A, Wt, b_g, q, k, v, g);
    attn_kernel<<<dim3(H, S), 512, 0, stream>>>(q, k, v, g, mask, zbp, o);
    out_gemm<<<NR / 128, 512, 0, stream>>>(o, Wt + (size_t)4 * 256 * 256, b_o, out);
}

// Round 5
// 377.454 us; speedup vs baseline: 9.3263x; 1.5784x over previous
//
#include <hip/hip_runtime.h>
#include <math.h>

#define S 128
#define R 384
#define CM 256
#define CZ 128
#define H 8
#define D 32
#define INFB 1e9f
#define LN_EPS 1e-5f

typedef unsigned short u16;
typedef short bf16x8 __attribute__((ext_vector_type(8)));
typedef float f32x4 __attribute__((ext_vector_type(4)));

__device__ inline float wave_reduce_sum(float v) {
    #pragma unroll
    for (int o = 32; o > 0; o >>= 1) v += __shfl_xor(v, o, 64);
    return v;
}

__device__ inline u16 f2bf(float f) {
    union { float f; unsigned int u; } x; x.f = f;
    unsigned int r = x.u + 0x7fffu + ((x.u >> 16) & 1u);
    return (u16)(r >> 16);
}

// ---------------------------------------------------------------------------
// Weight prep: Wt[mi][n][k] = src_mi[k][n] as bf16; mi: 0=q(scaled),1=k,2=v,3=g,4=o
__global__ __launch_bounds__(256) void wprep_kernel(
    const float* __restrict__ wq, const float* __restrict__ wk,
    const float* __restrict__ wv, const float* __restrict__ wg,
    const float* __restrict__ wo, u16* __restrict__ Wt) {
    int n = blockIdx.x & 255;
    int mi = blockIdx.x >> 8;
    int kc = threadIdx.x;
    const float* src = mi == 0 ? wq : mi == 1 ? wk : mi == 2 ? wv
                     : mi == 3 ? wg : wo;
    float val = src[(size_t)kc * 256 + n];
    if (mi == 0) val *= 0.17677669529663687f;  // 1/sqrt(32)
    Wt[((size_t)mi * 256 + n) * 256 + kc] = f2bf(val);
}

// ---------------------------------------------------------------------------
// LN(m) -> A bf16 [S*R][256]. 4 rows per block, wave per row.
__global__ __launch_bounds__(256) void lnm_kernel(
    const float* __restrict__ m, const float* __restrict__ lnw,
    const float* __restrict__ lnb, u16* __restrict__ A) {
    int t = threadIdx.x;
    int wave = t >> 6, lane = t & 63;
    size_t row = (size_t)blockIdx.x * 4 + wave;
    float4 x = ((const float4*)(m + row * 256))[lane];
    float ss = wave_reduce_sum(x.x + x.y + x.z + x.w);
    float sq = wave_reduce_sum(x.x * x.x + x.y * x.y + x.z * x.z + x.w * x.w);
    float mu = ss * (1.0f / 256.0f);
    float var = sq * (1.0f / 256.0f) - mu * mu;
    float rstd = rsqrtf(var + LN_EPS);
    int c = lane * 4;
    ushort4 o4;
    o4.x = f2bf((x.x - mu) * rstd * lnw[c]     + lnb[c]);
    o4.y = f2bf((x.y - mu) * rstd * lnw[c + 1] + lnb[c + 1]);
    o4.z = f2bf((x.z - mu) * rstd * lnw[c + 2] + lnb[c + 2]);
    o4.w = f2bf((x.w - mu) * rstd * lnw[c + 3] + lnb[c + 3]);
    ((ushort4*)(A + row * 256))[lane] = o4;
}

// ---------------------------------------------------------------------------
// z_bias v2: algebra-folded, 16 lanes per (i,j) pair, 4 pairs per wave.
// z_bias[h,p] = rstd_p * sum_c (z[p,c]-mu_p)*uw[c,h] + sum_c lnb[c]*wz[c,h]
// uw[c,h] = lnw[c]*wz[c,h] hoisted into registers per lane (8 ch x 8 heads).
// All math fp32 (exact vs reference up to reassociation).
__global__ __launch_bounds__(256) void zbias_kernel(
    const float* __restrict__ z, const float* __restrict__ lnw,
    const float* __restrict__ lnb, const float* __restrict__ wz,
    float* __restrict__ zbias) {
    int t = threadIdx.x;
    int lane = t & 63, wave = t >> 6;
    int g = lane >> 4, u = lane & 15;  // pair-group, lane-in-group
    int c0 = u * 8;                    // this lane's first channel

    // per-lane constants (pair-independent, hoisted)
    float lw[8], lb[8];
    {
        float4 a = *(const float4*)(lnw + c0);
        float4 b = *(const float4*)(lnw + c0 + 4);
        lw[0]=a.x; lw[1]=a.y; lw[2]=a.z; lw[3]=a.w;
        lw[4]=b.x; lw[5]=b.y; lw[6]=b.z; lw[7]=b.w;
        float4 c = *(const float4*)(lnb + c0);
        float4 d = *(const float4*)(lnb + c0 + 4);
        lb[0]=c.x; lb[1]=c.y; lb[2]=c.z; lb[3]=c.w;
        lb[4]=d.x; lb[5]=d.y; lb[6]=d.z; lb[7]=d.w;
    }
    float uw[8][8];   // uw[i][h]
    float bwp[8];     // partial sum lnb*wz
    #pragma unroll
    for (int h = 0; h < 8; ++h) bwp[h] = 0.f;
    #pragma unroll
    for (int i = 0; i < 8; ++i) {
        float4 w0 = *(const float4*)(wz + (size_t)(c0 + i) * 8);
        float4 w1 = *(const float4*)(wz + (size_t)(c0 + i) * 8 + 4);
        uw[i][0] = lw[i] * w0.x; uw[i][1] = lw[i] * w0.y;
        uw[i][2] = lw[i] * w0.z; uw[i][3] = lw[i] * w0.w;
        uw[i][4] = lw[i] * w1.x; uw[i][5] = lw[i] * w1.y;
        uw[i][6] = lw[i] * w1.z; uw[i][7] = lw[i] * w1.w;
        bwp[0] = fmaf(lb[i], w0.x, bwp[0]); bwp[1] = fmaf(lb[i], w0.y, bwp[1]);
        bwp[2] = fmaf(lb[i], w0.z, bwp[2]); bwp[3] = fmaf(lb[i], w0.w, bwp[3]);
        bwp[4] = fmaf(lb[i], w1.x, bwp[4]); bwp[5] = fmaf(lb[i], w1.y, bwp[5]);
        bwp[6] = fmaf(lb[i], w1.z, bwp[6]); bwp[7] = fmaf(lb[i], w1.w, bwp[7]);
    }

    const int nwaves = gridDim.x * 4;           // 2304*4 = 9216
    int wid = blockIdx.x * 4 + wave;
    #pragma unroll 1
    for (int it = 0; it < 4; ++it) {            // 9216*4*4 = 147456 pairs
        int p = (wid + it * nwaves) * 4 + g;
        const float* zp = z + (size_t)p * CZ + c0;
        float4 z0 = *(const float4*)zp;
        float4 z1 = *(const float4*)(zp + 4);
        float x[8] = {z0.x, z0.y, z0.z, z0.w, z1.x, z1.y, z1.z, z1.w};
        float ss = 0.f, sq = 0.f;
        #pragma unroll
        for (int i = 0; i < 8; ++i) { ss += x[i]; sq = fmaf(x[i], x[i], sq); }
        #pragma unroll
        for (int o = 1; o < 16; o <<= 1) {
            ss += __shfl_xor(ss, o, 64);
            sq += __shfl_xor(sq, o, 64);
        }
        float mu = ss * (1.0f / CZ);
        float var = sq * (1.0f / CZ) - mu * mu;
        float rstd = rsqrtf(var + LN_EPS);
        float ph[8];
        #pragma unroll
        for (int h = 0; h < 8; ++h) ph[h] = bwp[h];
        #pragma unroll
        for (int i = 0; i < 8; ++i) {
            float ti = (x[i] - mu) * rstd;
            #pragma unroll
            for (int h = 0; h < 8; ++h) ph[h] = fmaf(ti, uw[i][h], ph[h]);
        }
        #pragma unroll
        for (int h = 0; h < 8; ++h) {
            #pragma unroll
            for (int o = 1; o < 16; o <<= 1) ph[h] += __shfl_xor(ph[h], o, 64);
        }
        if (u < 8) {
            float outv = ph[0];
            if (u == 1) outv = ph[1];
            if (u == 2) outv = ph[2];
            if (u == 3) outv = ph[3];
            if (u == 4) outv = ph[4];
            if (u == 5) outv = ph[5];
            if (u == 6) outv = ph[6];
            if (u == 7) outv = ph[7];
            zbias[(size_t)u * (R * R) + p] = outv;
        }
    }
}

// ---------------------------------------------------------------------------
// qkvg GEMM: M=49152, K=256, one weight matrix per blockIdx.y.
// 512 thr / 8 waves, BM=128, wave tile 64x64, no LDS, no barriers.
__global__ __launch_bounds__(512) void qkvg_gemm(
    const u16* __restrict__ A, const u16* __restrict__ Wt,
    const float* __restrict__ bg,
    u16* __restrict__ q, u16* __restrict__ k, u16* __restrict__ v,
    float* __restrict__ g) {
    int nb = blockIdx.y;
    size_t row0 = (size_t)blockIdx.x * 128;
    int t = threadIdx.x, lane = t & 63, wave = t >> 6;
    int l15 = lane & 15, l4 = lane >> 4;
    int wm = (wave >> 2) * 64, wn = (wave & 3) * 64;
    const u16* B = Wt + (size_t)nb * 256 * 256;
    const u16* Ab = A + (row0 + wm + l15) * 256 + l4 * 8;
    const u16* Bb = B + (size_t)(wn + l15) * 256 + l4 * 8;

    f32x4 acc[4][4];
    #pragma unroll
    for (int mt = 0; mt < 4; ++mt)
        #pragma unroll
        for (int nt = 0; nt < 4; ++nt)
            acc[mt][nt] = (f32x4){0.f, 0.f, 0.f, 0.f};

    #pragma unroll
    for (int kk = 0; kk < 8; ++kk) {
        bf16x8 af[4], bfr[4];
        #pragma unroll
        for (int mt = 0; mt < 4; ++mt)
            af[mt] = *(const bf16x8*)(Ab + (size_t)mt * 16 * 256 + kk * 32);
        #pragma unroll
        for (int nt = 0; nt < 4; ++nt)
            bfr[nt] = *(const bf16x8*)(Bb + (size_t)nt * 16 * 256 + kk * 32);
        #pragma unroll
        for (int mt = 0; mt < 4; ++mt)
            #pragma unroll
            for (int nt = 0; nt < 4; ++nt)
                acc[mt][nt] = __builtin_amdgcn_mfma_f32_16x16x32_bf16(
                    af[mt], bfr[nt], acc[mt][nt], 0, 0, 0);
    }

    if (nb == 3) {
        #pragma unroll
        for (int nt = 0; nt < 4; ++nt) {
            int col = wn + nt * 16 + l15;
            float bgv = bg[col];
            #pragma unroll
            for (int mt = 0; mt < 4; ++mt)
                #pragma unroll
                for (int r = 0; r < 4; ++r) {
                    size_t row = row0 + wm + mt * 16 + l4 * 4 + r;
                    g[row * 256 + col] =
                        1.0f / (1.0f + __expf(-(acc[mt][nt][r] + bgv)));
                }
        }
    } else {
        u16* dst = nb == 0 ? q : nb == 1 ? k : v;
        #pragma unroll
        for (int nt = 0; nt < 4; ++nt) {
            int col = wn + nt * 16 + l15;
            #pragma unroll
            for (int mt = 0; mt < 4; ++mt)
                #pragma unroll
                for (int r = 0; r < 4; ++r) {
                    size_t row = row0 + wm + mt * 16 + l4 * 4 + r;
                    dst[row * 256 + col] = f2bf(acc[mt][nt][r]);
                }
        }
    }
}

// ---------------------------------------------------------------------------
// out GEMM: M=49152, N=256, K=256; A = o (bf16), +b_o, fp32 out.
__global__ __launch_bounds__(512) void out_gemm(
    const u16* __restrict__ A, const u16* __restrict__ Wt,
    const float* __restrict__ bo, float* __restrict__ out) {
    size_t row0 = (size_t)blockIdx.x * 128;
    int t = threadIdx.x, lane = t & 63, wave = t >> 6;
    int l15 = lane & 15, l4 = lane >> 4;
    int wm = (wave >> 2) * 64, wn = (wave & 3) * 64;
    const u16* Ab = A + (row0 + wm + l15) * 256 + l4 * 8;
    const u16* Bb = Wt + (size_t)(wn + l15) * 256 + l4 * 8;

    f32x4 acc[4][4];
    #pragma unroll
    for (int mt = 0; mt < 4; ++mt)
        #pragma unroll
        for (int nt = 0; nt < 4; ++nt)
            acc[mt][nt] = (f32x4){0.f, 0.f, 0.f, 0.f};

    #pragma unroll
    for (int kk = 0; kk < 8; ++kk) {
        bf16x8 af[4], bfr[4];
        #pragma unroll
        for (int mt = 0; mt < 4; ++mt)
            af[mt] = *(const bf16x8*)(Ab + (size_t)mt * 16 * 256 + kk * 32);
        #pragma unroll
        for (int nt = 0; nt < 4; ++nt)
            bfr[nt] = *(const bf16x8*)(Bb + (size_t)nt * 16 * 256 + kk * 32);
        #pragma unroll
        for (int mt = 0; mt < 4; ++mt)
            #pragma unroll
            for (int nt = 0; nt < 4; ++nt)
                acc[mt][nt] = __builtin_amdgcn_mfma_f32_16x16x32_bf16(
                    af[mt], bfr[nt], acc[mt][nt], 0, 0, 0);
    }

    #pragma unroll
    for (int nt = 0; nt < 4; ++nt) {
        int col = wn + nt * 16 + l15;
        float bov = bo[col];
        #pragma unroll
        for (int mt = 0; mt < 4; ++mt)
            #pragma unroll
            for (int r = 0; r < 4; ++r) {
                size_t row = row0 + wm + mt * 16 + l4 * 4 + r;
                out[row * 256 + col] = acc[mt][nt][r] + bov;
            }
    }
}

// ---------------------------------------------------------------------------
// Attention: MFMA bf16, one block (512 thr, 8 waves) per (s, h).
__global__ __launch_bounds__(512) void attn_kernel(
    const u16* __restrict__ q, const u16* __restrict__ k,
    const u16* __restrict__ v, const float* __restrict__ g,
    const float* __restrict__ mask, const float* __restrict__ zb,
    u16* __restrict__ o) {
    int h = blockIdx.x, s = blockIdx.y;
    int t = threadIdx.x;
    int lane = t & 63, wave = t >> 6;
    int l15 = lane & 15, l4 = lane >> 4;

    __shared__ __attribute__((aligned(16))) u16 VTsh[32 * 408];
    __shared__ __attribute__((aligned(16))) u16 Psh[8 * 48 * 32];

    size_t base = ((size_t)s * R) * 256 + (size_t)h * 32;  // bf16 elem offset

    for (int it = 0; it < 6; ++it) {
        int idx = t + it * 512;
        int key = idx >> 3;
        int c4 = (idx & 7) << 2;
        ushort4 vv = *(const ushort4*)(v + base + (size_t)key * 256 + c4);
        VTsh[(c4 + 0) * 408 + key] = vv.x;
        VTsh[(c4 + 1) * 408 + key] = vv.y;
        VTsh[(c4 + 2) * 408 + key] = vv.z;
        VTsh[(c4 + 3) * 408 + key] = vv.w;
    }

    int wq0 = wave * 48;
    bf16x8 qf[3];
    #pragma unroll
    for (int rt = 0; rt < 3; ++rt)
        qf[rt] = *(const bf16x8*)(q + base +
                                  (size_t)(wq0 + rt * 16 + l15) * 256 + l4 * 8);
    __syncthreads();  // VTsh ready

    f32x4 oacc[3][2];
    #pragma unroll
    for (int rt = 0; rt < 3; ++rt)
        #pragma unroll
        for (int dt = 0; dt < 2; ++dt)
            oacc[rt][dt] = (f32x4){0.f, 0.f, 0.f, 0.f};
    float pden[3][4] = {};

    const float* zbh = zb + (size_t)h * R * R;
    const int pbase = wave * 1536;

    for (int kt = 0; kt < R; kt += 32) {
        bf16x8 kf[2];
        float mv[2];
        #pragma unroll
        for (int ct = 0; ct < 2; ++ct) {
            int key = kt + ct * 16 + l15;
            kf[ct] = *(const bf16x8*)(k + base + (size_t)key * 256 + l4 * 8);
            mv[ct] = INFB * (mask[(size_t)s * R + key] - 1.0f);
        }

        const f32x4 z4 = {0.f, 0.f, 0.f, 0.f};
        f32x4 sfr[3][2];
        #pragma unroll
        for (int rt = 0; rt < 3; ++rt)
            #pragma unroll
            for (int ct = 0; ct < 2; ++ct)
                sfr[rt][ct] = __builtin_amdgcn_mfma_f32_16x16x32_bf16(
                    qf[rt], kf[ct], z4, 0, 0, 0);

        #pragma unroll
        for (int rt = 0; rt < 3; ++rt) {
            #pragma unroll
            for (int ct = 0; ct < 2; ++ct) {
                #pragma unroll
                for (int r = 0; r < 4; ++r) {
                    int row = rt * 16 + l4 * 4 + r;
                    int key = kt + ct * 16 + l15;
                    float zv = zbh[(size_t)(wq0 + row) * R + key];
                    float e = __expf(sfr[rt][ct][r] + mv[ct] + zv);
                    pden[rt][r] += e;
                    int ei = (row * 32 + ct * 16 + l15) ^ (((row >> 2) & 3) << 4);
                    Psh[pbase + ei] = f2bf(e);
                }
            }
        }

        #pragma unroll
        for (int rt = 0; rt < 3; ++rt) {
            int row = rt * 16 + l15;
            int ei = (row * 32 + l4 * 8) ^ (((row >> 2) & 3) << 4);
            bf16x8 pa = *(const bf16x8*)&Psh[pbase + ei];
            #pragma unroll
            for (int dt = 0; dt < 2; ++dt) {
                bf16x8 vbf = *(const bf16x8*)&VTsh[(dt * 16 + l15) * 408 + kt + l4 * 8];
                oacc[rt][dt] = __builtin_amdgcn_mfma_f32_16x16x32_bf16(
                    pa, vbf, oacc[rt][dt], 0, 0, 0);
            }
        }
    }

    #pragma unroll
    for (int rt = 0; rt < 3; ++rt)
        #pragma unroll
        for (int r = 0; r < 4; ++r) {
            float d = pden[rt][r];
            d += __shfl_xor(d, 1, 64);
            d += __shfl_xor(d, 2, 64);
            d += __shfl_xor(d, 4, 64);
            d += __shfl_xor(d, 8, 64);
            pden[rt][r] = d;
        }

    #pragma unroll
    for (int rt = 0; rt < 3; ++rt) {
        #pragma unroll
        for (int r = 0; r < 4; ++r) {
            float inv = 1.0f / pden[rt][r];
            int qrow = wq0 + rt * 16 + l4 * 4 + r;
            #pragma unroll
            for (int dt = 0; dt < 2; ++dt) {
                size_t off = base + (size_t)qrow * 256 + dt * 16 + l15;
                o[off] = f2bf(oacc[rt][dt][r] * inv * g[off]);
            }
        }
    }
}

extern "C" void kernel_launch(void* const* d_in, const int* in_sizes, int n_in,
                              void* d_out, int out_size, void* d_ws, size_t ws_size,
                              hipStream_t stream) {
    (void)in_sizes; (void)n_in; (void)out_size; (void)ws_size;
    const float* m      = (const float*)d_in[0];
    const float* z      = (const float*)d_in[1];
    const float* mask   = (const float*)d_in[2];
    const float* ln_m_w = (const float*)d_in[3];
    const float* ln_m_b = (const float*)d_in[4];
    const float* ln_z_w = (const float*)d_in[5];
    const float* ln_z_b = (const float*)d_in[6];
    const float* w_z    = (const float*)d_in[7];
    const float* w_q    = (const float*)d_in[8];
    const float* w_k    = (const float*)d_in[9];
    const float* w_v    = (const float*)d_in[10];
    const float* w_g    = (const float*)d_in[11];
    const float* b_g    = (const float*)d_in[12];
    const float* w_o    = (const float*)d_in[13];
    const float* b_o    = (const float*)d_in[14];
    float* out = (float*)d_out;
    char* wsb = (char*)d_ws;

    const size_t NR = (size_t)S * R;  // 49152 rows
    u16*   A   = (u16*)wsb;                      wsb += NR * 256 * 2;
    u16*   q   = (u16*)wsb;                      wsb += NR * 256 * 2;
    u16*   k   = (u16*)wsb;                      wsb += NR * 256 * 2;
    u16*   v   = (u16*)wsb;                      wsb += NR * 256 * 2;
    u16*   o   = (u16*)wsb;                      wsb += NR * 256 * 2;
    float* g   = (float*)wsb;                    wsb += NR * 256 * 4;
    float* zbp = (float*)wsb;                    wsb += (size_t)H * R * R * 4;
    u16*   Wt  = (u16*)wsb;                      wsb += (size_t)5 * 256 * 256 * 2;

    wprep_kernel<<<5 * 256, 256, 0, stream>>>(w_q, w_k, w_v, w_g, w_o, Wt);
    lnm_kernel<<<NR / 4, 256, 0, stream>>>(m, ln_m_w, ln_m_b, A);
    zbias_kernel<<<2304, 256, 0, stream>>>(z, ln_z_w, ln_z_b, w_z, zbp);
    qkvg_gemm<<<dim3(NR / 128, 4), 512, 0, stream>>>(A, Wt, b_g, q, k, v, g);
    attn_kernel<<<dim3(H, S), 512, 0, stream>>>(q, k, v, g, mask, zbp, o);
    out_gemm<<<NR / 128, 512, 0, stream>>>(o, Wt + (size_t)4 * 256 * 256, b_o, out);
}